// Round 1
// baseline (295.193 us; speedup 1.0000x reference)
//
#include <hip/hip_runtime.h>
#include <math.h>

#define FRAME_LEN 512
#define HOP       128
#define NFFT      512
#define NBINS     257
#define NFRAMES   4000
#define NB        16

// One block per frame: 256 threads, radix-2 DIT inverse FFT of the
// Hermitian-extended 512-point spectrum in LDS, windowed overlap-add
// via atomicAdd into the output.
__global__ __launch_bounds__(256)
void istft_ola_kernel(const float* __restrict__ re,
                      const float* __restrict__ im,
                      float* __restrict__ out,
                      int out_len)
{
    __shared__ float sre[NFFT];
    __shared__ float sim[NFFT];

    const int f   = blockIdx.x;          // global frame index
    const int b   = f / NFRAMES;
    const int fr  = f - b * NFRAMES;
    const int tid = threadIdx.x;         // 0..255

    const float* __restrict__ rbase = re + (size_t)f * NBINS;
    const float* __restrict__ ibase = im + (size_t)f * NBINS;

    // Build full spectrum Y[0..511] with Hermitian symmetry, storing into
    // bit-reversed LDS positions. Taking Re() at the end makes this exactly
    // equal to irfft (Im of DC/Nyquist drop out).
    #pragma unroll
    for (int t = tid; t < NFFT; t += 256) {
        float xr, xi;
        if (t <= NFFT / 2) { xr = rbase[t];        xi =  ibase[t]; }
        else               { xr = rbase[NFFT - t]; xi = -ibase[NFFT - t]; }
        int p = (int)(__brev((unsigned)t) >> 23);  // 9-bit bit reverse
        sre[p] = xr;
        sim[p] = xi;
    }
    __syncthreads();

    // 9 radix-2 DIT stages, inverse sign: w = e^{+i 2*pi*j/m}
    #pragma unroll
    for (int s = 1; s <= 9; ++s) {
        const int half = 1 << (s - 1);
        const int j    = tid & (half - 1);
        const int k    = ((tid >> (s - 1)) << s) + j;
        const float ang = 6.2831853071795864f * (float)j / (float)(1 << s);
        float wi, wr;
        __sincosf(ang, &wi, &wr);                 // wi = sin, wr = cos
        const float ur = sre[k],        ui = sim[k];
        const float vr = sre[k + half], vi = sim[k + half];
        const float tr = vr * wr - vi * wi;
        const float ti = vr * wi + vi * wr;
        sre[k]        = ur + tr;
        sim[k]        = ui + ti;
        sre[k + half] = ur - tr;
        sim[k + half] = ui - ti;
        __syncthreads();
    }

    // Windowed overlap-add. inverse_window[n] = hann[n] / denom[n % HOP],
    // denom[p] = sum_{o=0..3} hann[o*HOP + p]^2  (periodic Hann, N=512).
    const float inv_n = 1.0f / (float)NFFT;
    const long long base = (long long)b * out_len + (long long)fr * HOP;

    #pragma unroll
    for (int n = tid; n < FRAME_LEN; n += 256) {
        const float wn = 0.5f - 0.5f * __cosf(6.2831853071795864f * (float)n / 512.0f);
        const int p = n & (HOP - 1);
        float denom = 0.0f;
        #pragma unroll
        for (int o = 0; o < 4; ++o) {
            const float w2 = 0.5f - 0.5f * __cosf(6.2831853071795864f * (float)(o * HOP + p) / 512.0f);
            denom += w2 * w2;
        }
        const float val = sre[n] * inv_n * wn / denom;
        if (fr * HOP + n < out_len) {
            atomicAdd(&out[base + n], val);
        }
    }
}

extern "C" void kernel_launch(void* const* d_in, const int* in_sizes, int n_in,
                              void* d_out, int out_size, void* d_ws, size_t ws_size,
                              hipStream_t stream) {
    (void)in_sizes; (void)n_in; (void)d_ws; (void)ws_size;
    const float* re = (const float*)d_in[0];
    const float* im = (const float*)d_in[1];
    float* out = (float*)d_out;

    const int out_len = out_size / NB;   // 512383 = (4000-1)*128 + 512 - 1

    // Harness poisons d_out with 0xAA before every timed launch; OLA needs zeros.
    hipMemsetAsync(d_out, 0, (size_t)out_size * sizeof(float), stream);

    istft_ola_kernel<<<dim3(NB * NFRAMES), dim3(256), 0, stream>>>(re, im, out, out_len);
}

// Round 2
// 177.356 us; speedup vs baseline: 1.6644x; 1.6644x over previous
//
#include <hip/hip_runtime.h>
#include <math.h>

#define HOP       128
#define NFFT      512
#define NBINS     257
#define NFRAMES   4000
#define NB        16
#define OUT_LEN   512383          // (4000-1)*128 + 512 - 1
#define CPR       16              // chunks per range (per wave)
#define RPB       251             // ranges per batch = ceil(4003/16)
#define NCHUNK    4003            // output chunks of 128 (last is 127)
#define SP        66              // P layout pad stride (float2 units)
#define SQ        65              // Q layout pad stride
#define PBUF      528             // per-wave scratch size (float2)

// Inverse (e^{+i}) 8-point DFT, DIF with output bit-reversal folded in.
__device__ __forceinline__ void dft8_inv(const float* xr, const float* xi,
                                         float* yr, float* yi)
{
    const float C = 0.70710678118654752f;
    float ar[8], ai[8];
    ar[0]=xr[0]+xr[4]; ai[0]=xi[0]+xi[4];
    ar[1]=xr[1]+xr[5]; ai[1]=xi[1]+xi[5];
    ar[2]=xr[2]+xr[6]; ai[2]=xi[2]+xi[6];
    ar[3]=xr[3]+xr[7]; ai[3]=xi[3]+xi[7];
    float t0r=xr[0]-xr[4], t0i=xi[0]-xi[4];
    float t1r=xr[1]-xr[5], t1i=xi[1]-xi[5];
    float t2r=xr[2]-xr[6], t2i=xi[2]-xi[6];
    float t3r=xr[3]-xr[7], t3i=xi[3]-xi[7];
    ar[4]= t0r;            ai[4]= t0i;             // *W8^0
    ar[5]= C*(t1r-t1i);    ai[5]= C*(t1r+t1i);     // *W8^1 = C(1+i)
    ar[6]=-t2i;            ai[6]= t2r;             // *W8^2 = i
    ar[7]=-C*(t3r+t3i);    ai[7]= C*(t3r-t3i);     // *W8^3 = C(-1+i)
    float br[8], bi[8];
    br[0]=ar[0]+ar[2]; bi[0]=ai[0]+ai[2];
    br[1]=ar[1]+ar[3]; bi[1]=ai[1]+ai[3];
    br[2]=ar[0]-ar[2]; bi[2]=ai[0]-ai[2];
    { float u=ar[1]-ar[3], v=ai[1]-ai[3]; br[3]=-v; bi[3]=u; }   // *i
    br[4]=ar[4]+ar[6]; bi[4]=ai[4]+ai[6];
    br[5]=ar[5]+ar[7]; bi[5]=ai[5]+ai[7];
    br[6]=ar[4]-ar[6]; bi[6]=ai[4]-ai[6];
    { float u=ar[5]-ar[7], v=ai[5]-ai[7]; br[7]=-v; bi[7]=u; }   // *i
    // final radix-2 + bitrev3 output placement
    yr[0]=br[0]+br[1]; yi[0]=bi[0]+bi[1];
    yr[4]=br[0]-br[1]; yi[4]=bi[0]-bi[1];
    yr[2]=br[2]+br[3]; yi[2]=bi[2]+bi[3];
    yr[6]=br[2]-br[3]; yi[6]=bi[2]-bi[3];
    yr[1]=br[4]+br[5]; yi[1]=bi[4]+bi[5];
    yr[5]=br[4]-br[5]; yi[5]=bi[4]-bi[5];
    yr[3]=br[6]+br[7]; yi[3]=bi[6]+bi[7];
    yr[7]=br[6]-br[7]; yi[7]=bi[6]-bi[7];
}

// One wave per chunk-range: 16 output chunks + 3 halo frames, radix-8
// 512-pt inverse FFT (3 stages, 2 LDS round-trips), register shift-
// accumulator overlap-add, coalesced exactly-once stores. No atomics.
__global__ __launch_bounds__(256)
void istft_r8_kernel(const float* __restrict__ re,
                     const float* __restrict__ im,
                     float* __restrict__ out)
{
    __shared__ float  wtab[NFFT];
    __shared__ float2 pbuf[4][PBUF];

    const int tid = threadIdx.x;
    const int wv  = tid >> 6;
    const int l   = tid & 63;

    // Window table: win[n]/(512 * denom[n%128]) — includes irfft 1/N.
    for (int n = tid; n < NFFT; n += 256) {
        const float wn = 0.5f - 0.5f * __cosf(6.2831853071795864f * (float)n * (1.0f/512.0f));
        const int p = n & (HOP - 1);
        float denom = 0.0f;
        #pragma unroll
        for (int o = 0; o < 4; ++o) {
            const float w2 = 0.5f - 0.5f * __cosf(6.2831853071795864f * (float)(o*HOP + p) * (1.0f/512.0f));
            denom += w2 * w2;
        }
        wtab[n] = wn / (512.0f * denom);
    }
    __syncthreads();

    float2* P = pbuf[wv];

    const int rid = blockIdx.x * 4 + wv;
    const int b   = rid / RPB;
    const int rr  = rid - b * RPB;
    const int c0  = rr * CPR;
    const int fend = min(c0 + CPR - 1, NCHUNK - 1);

    const float* __restrict__ reb = re + (size_t)b * NFRAMES * NBINS;
    const float* __restrict__ imb = im + (size_t)b * NFRAMES * NBINS;
    float* __restrict__ outb = out + (size_t)b * OUT_LEN;

    // Frame-invariant twiddles.
    // Stage 1: e^{+i 2pi n0 l / 512}, n0 = 0..7
    float s1r[8], s1i[8];
    {
        float sr, cr;
        __sincosf(6.2831853071795864f * (float)l * (1.0f/512.0f), &sr, &cr);
        s1r[0] = 1.0f; s1i[0] = 0.0f; s1r[1] = cr; s1i[1] = sr;
        #pragma unroll
        for (int k = 2; k < 8; ++k) {
            s1r[k] = s1r[k-1]*cr - s1i[k-1]*sr;
            s1i[k] = s1r[k-1]*sr + s1i[k-1]*cr;
        }
    }
    // Stage 2: e^{+i 2pi m0 (l&7) / 64}, m0 = 0..7
    float s2r[8], s2i[8];
    {
        float sr, cr;
        __sincosf(6.2831853071795864f * (float)(l & 7) * (1.0f/64.0f), &sr, &cr);
        s2r[0] = 1.0f; s2i[0] = 0.0f; s2r[1] = cr; s2i[1] = sr;
        #pragma unroll
        for (int k = 2; k < 8; ++k) {
            s2r[k] = s2r[k-1]*cr - s2i[k-1]*sr;
            s2i[k] = s2r[k-1]*sr + s2i[k-1]*cr;
        }
    }
    // Lane's window weights (output n = l + 64*m1).
    float ww[8];
    #pragma unroll
    for (int m1 = 0; m1 < 8; ++m1) ww[m1] = wtab[l + 64*m1];

    float acc[8];
    #pragma unroll
    for (int r = 0; r < 8; ++r) acc[r] = 0.0f;

    const int n0s = l >> 3, gs = l & 7;   // stage-2 lane assignment
    const int m0t = l >> 3, n0t = l & 7;  // stage-3 lane assignment

    for (int f = c0 - 3; f <= fend; ++f) {
        if (f >= 0 && f < NFRAMES) {
            const float* __restrict__ rb = reb + (size_t)f * NBINS;
            const float* __restrict__ ib = imb + (size_t)f * NBINS;

            // Load x[64a + l], Hermitian-extended, branchless.
            float xr[8], xi[8];
            #pragma unroll
            for (int a = 0; a < 8; ++a) {
                const int t  = 64*a + l;
                const int tt = (t <= 256) ? t : (512 - t);
                const float sg = (t <= 256) ? 1.0f : -1.0f;
                xr[a] = rb[tt];
                xi[a] = sg * ib[tt];
            }

            // Stage 1: DFT8 over a -> p[n0]; twiddle W512^{n0 l}; store.
            float pr[8], pi[8];
            dft8_inv(xr, xi, pr, pi);
            #pragma unroll
            for (int n0 = 0; n0 < 8; ++n0) {
                const float tr = pr[n0]*s1r[n0] - pi[n0]*s1i[n0];
                const float ti = pr[n0]*s1i[n0] + pi[n0]*s1r[n0];
                P[SP*n0 + l] = make_float2(tr, ti);
            }
            __builtin_amdgcn_wave_barrier();

            // Stage 2: gather p[n0s][8e+gs], DFT8 over e, twiddle W64^{m0 gs}, store.
            #pragma unroll
            for (int e = 0; e < 8; ++e) {
                const float2 v = P[SP*n0s + 8*e + gs];
                xr[e] = v.x; xi[e] = v.y;
            }
            __builtin_amdgcn_wave_barrier();
            float qr[8], qi[8];
            dft8_inv(xr, xi, qr, qi);
            #pragma unroll
            for (int m0 = 0; m0 < 8; ++m0) {
                const float tr = qr[m0]*s2r[m0] - qi[m0]*s2i[m0];
                const float ti = qr[m0]*s2i[m0] + qi[m0]*s2r[m0];
                P[SQ*m0 + l] = make_float2(tr, ti);   // == SQ*m0 + 8*n0s + gs
            }
            __builtin_amdgcn_wave_barrier();

            // Stage 3: gather q[n0t][m0t][g], DFT8 over g -> X[l + 64*m1].
            #pragma unroll
            for (int g = 0; g < 8; ++g) {
                const float2 v = P[SQ*m0t + 8*n0t + g];
                xr[g] = v.x; xi[g] = v.y;
            }
            __builtin_amdgcn_wave_barrier();
            float yr[8], yi[8];
            dft8_inv(xr, xi, yr, yi);

            // Window + accumulate (real part only).
            #pragma unroll
            for (int m1 = 0; m1 < 8; ++m1) acc[m1] += yr[m1] * ww[m1];
        }

        // Emit chunk f (positions f*128 + {0..127}) — complete after adding frame f.
        if (f >= c0) {
            const int pos0 = f * HOP + l;        // max 512319 < OUT_LEN, always valid
            const int pos1 = pos0 + 64;          // max 512383 == OUT_LEN at the very end
            outb[pos0] = acc[0];
            if (pos1 < OUT_LEN) outb[pos1] = acc[1];
        }

        // Shift the accumulator window forward by 128 samples (2 slots).
        #pragma unroll
        for (int r = 0; r < 6; ++r) acc[r] = acc[r + 2];
        acc[6] = 0.0f; acc[7] = 0.0f;
    }
}

extern "C" void kernel_launch(void* const* d_in, const int* in_sizes, int n_in,
                              void* d_out, int out_size, void* d_ws, size_t ws_size,
                              hipStream_t stream) {
    (void)in_sizes; (void)n_in; (void)d_ws; (void)ws_size; (void)out_size;
    const float* re = (const float*)d_in[0];
    const float* im = (const float*)d_in[1];
    float* out = (float*)d_out;

    // 16 batches x 251 ranges = 4016 waves; 4 waves per 256-thread block.
    const int nblocks = (NB * RPB) / 4;   // 1004
    istft_r8_kernel<<<dim3(nblocks), dim3(256), 0, stream>>>(re, im, out);
}